// Round 7
// baseline (948.101 us; speedup 1.0000x reference)
//
#include <hip/hip_runtime.h>
#include <cmath>

// SimplifiedSSM: B=2, L=2048, d_model=768, d_state=16, d_inner=1536
// ROUND 7: MFMA pipeline (math verified vs 2 independent cores in R2-R6),
// output stored as FP32 (R2-R6 failure was writing bf16 into an f32 out buffer).
#define DMODEL 768
#define DINNER 1536
#define NSTATE 16
#define SEQL   2048
#define LDSS   56   // LDS row stride in shorts: 112B -> every row 16B-aligned

#define DT_F32  0
#define DT_BF16 1
#define DT_ZERO 2

typedef __bf16 bf16x8 __attribute__((ext_vector_type(8)));
typedef float  f32x4  __attribute__((ext_vector_type(4)));

__device__ __forceinline__ float bf2f(unsigned short h) {
    union { unsigned u; float f; } v; v.u = ((unsigned)h) << 16; return v.f;
}
__device__ __forceinline__ unsigned short f2bf(float f) {
    union { float f; unsigned u; } v; v.f = f;
    unsigned r = (v.u + 0x7FFFu + ((v.u >> 16) & 1u)) >> 16;
    return (unsigned short)r;
}
// Robust per-array dtype sniff (kept as insurance; R6 established all-f32).
__device__ int detect_dtype(const void* p) {
    const unsigned* u = (const unsigned*)p;
    int nzlo = 0, band = 0, anynz = 0;
    for (int i = 0; i < 64; ++i) {
        unsigned w = u[i];
        anynz |= (w != 0);
        unsigned lo = w & 0xFFFFu;
        if (lo) {
            ++nzlo;
            unsigned e8 = (lo >> 7) & 0xFF;
            if (e8 >= 0x60 && e8 <= 0x8E) ++band;
        }
    }
    if (nzlo >= 8) return (band * 2 > nzlo) ? DT_BF16 : DT_F32;
    return anynz ? DT_F32 : DT_ZERO;
}
__device__ __forceinline__ float LD(const void* p, size_t i, int dt) {
    if (dt == DT_BF16) return bf2f(((const unsigned short*)p)[i]);
    if (dt == DT_F32)  return ((const float*)p)[i];
    return 0.f;
}

// ---- x -> bf16. n = 4096*768, 4 elems/thread ----
__global__ __launch_bounds__(256) void cvt_x_kernel(
    const void* __restrict__ x, unsigned short* __restrict__ xb)
{
    __shared__ int s_dt;
    if (threadIdx.x == 0) s_dt = detect_dtype(x);
    __syncthreads();
    const int dt = s_dt;
    size_t i = ((size_t)blockIdx.x * 256 + threadIdx.x) * 4;
    ushort4 o;
    o.x = f2bf(LD(x, i + 0, dt)); o.y = f2bf(LD(x, i + 1, dt));
    o.z = f2bf(LD(x, i + 2, dt)); o.w = f2bf(LD(x, i + 3, dt));
    *(ushort4*)&xb[i] = o;
}

// ---- small params -> f32: cw(4608) cb(1536) db(1536) A_log(24576) D(1536) xproj(49152) ----
__global__ __launch_bounds__(256) void cvt_params_kernel(
    const void* cw, const void* cb, const void* db, const void* Al,
    const void* Dv, const void* xp, float* __restrict__ out)
{
    __shared__ int dts[6];
    if (threadIdx.x == 0) {
        dts[0] = detect_dtype(cw); dts[1] = detect_dtype(cb);
        dts[2] = detect_dtype(db); dts[3] = detect_dtype(Al);
        dts[4] = detect_dtype(Dv); dts[5] = detect_dtype(xp);
    }
    __syncthreads();
    int g = blockIdx.x * 256 + threadIdx.x;
    if (g >= 82944) return;
    const void* src; int local; int which;
    if      (g <  4608) { src = cw; local = g;         which = 0; }
    else if (g <  6144) { src = cb; local = g - 4608;  which = 1; }
    else if (g <  7680) { src = db; local = g - 6144;  which = 2; }
    else if (g < 32256) { src = Al; local = g - 7680;  which = 3; }
    else if (g < 33792) { src = Dv; local = g - 32256; which = 4; }
    else                { src = xp; local = g - 33792; which = 5; }
    out[g] = LD(src, local, dts[which]);
}

// ---- transpose: in[R][C] -> out[C][R] bf16 ----
__global__ __launch_bounds__(256) void transpose_any(
    const void* __restrict__ in, unsigned short* __restrict__ out, int R, int C)
{
    __shared__ unsigned short tile[32][33];
    __shared__ int s_dt;
    if (threadIdx.x == 0) s_dt = detect_dtype(in);
    __syncthreads();
    const int dt = s_dt;
    const int t = threadIdx.x;
    const int tx = t & 31, ty = t >> 5;            // 32 x 8
    const int bx = blockIdx.x * 32, by = blockIdx.y * 32;
    #pragma unroll
    for (int i = 0; i < 4; ++i) {
        int r = by + ty + i * 8;
        tile[ty + i * 8][tx] = f2bf(LD(in, (size_t)r * C + bx + tx, dt));
    }
    __syncthreads();
    #pragma unroll
    for (int i = 0; i < 4; ++i) {
        int c = bx + ty + i * 8;
        out[(size_t)c * R + by + tx] = tile[tx][ty + i * 8];
    }
}

// ---- MFMA GEMM: C = A[M][K] @ Bt[N][K]^T (both bf16, k-contiguous) ----
// EPI 1: bf16 C0 = softplus(v + biasf[col])
// EPI 2: f32  C0 = v                       (final output)
// EPI 3: col < N/2 -> bf16 C0 = v ; else bf16 C1 = silu(v)
template<int EPI>
__global__ __launch_bounds__(256) void gemm_kernel(
    const unsigned short* __restrict__ A, const unsigned short* __restrict__ Bt,
    void* __restrict__ C0, void* __restrict__ C1, const float* __restrict__ biasf,
    int M, int N, int K)
{
    __shared__ __align__(16) unsigned short As[128 * LDSS];
    __shared__ __align__(16) unsigned short Bs[128 * LDSS];
    const int t    = threadIdx.x;
    const int m0   = blockIdx.x * 128;
    const int n0   = blockIdx.y * 128;
    const int w    = t >> 6;
    const int lane = t & 63;
    const int wm   = (w >> 1) * 64, wn = (w & 1) * 64;
    const int lm   = lane & 15, quad = lane >> 4;

    f32x4 acc[4][4] = {};

    for (int k0 = 0; k0 < K; k0 += 32) {
        #pragma unroll
        for (int i = 0; i < 2; ++i) {
            int id = t + i * 256;
            int r = id >> 2, c = (id & 3) * 8;
            *(uint4*)&As[r * LDSS + c] = *(const uint4*)&A[(size_t)(m0 + r) * K + k0 + c];
            *(uint4*)&Bs[r * LDSS + c] = *(const uint4*)&Bt[(size_t)(n0 + r) * K + k0 + c];
        }
        __syncthreads();
        bf16x8 af[4], bfr[4];
        #pragma unroll
        for (int i = 0; i < 4; ++i)
            af[i] = *(const bf16x8*)&As[(wm + i * 16 + lm) * LDSS + quad * 8];
        #pragma unroll
        for (int j = 0; j < 4; ++j)
            bfr[j] = *(const bf16x8*)&Bs[(wn + j * 16 + lm) * LDSS + quad * 8];
        #pragma unroll
        for (int i = 0; i < 4; ++i)
            #pragma unroll
            for (int j = 0; j < 4; ++j)
                acc[i][j] = __builtin_amdgcn_mfma_f32_16x16x32_bf16(af[i], bfr[j], acc[i][j], 0, 0, 0);
        __syncthreads();
    }

    const int half = N >> 1;
    #pragma unroll
    for (int i = 0; i < 4; ++i) {
        #pragma unroll
        for (int j = 0; j < 4; ++j) {
            int col = n0 + wn + j * 16 + lm;
            #pragma unroll
            for (int r = 0; r < 4; ++r) {
                int row = m0 + wm + i * 16 + quad * 4 + r;
                float v = acc[i][j][r];
                if (EPI == 1) {
                    v += biasf[col];
                    float sp = (v > 20.f) ? v : log1pf(__expf(v));
                    ((unsigned short*)C0)[(size_t)row * N + col] = f2bf(sp);
                } else if (EPI == 2) {
                    ((float*)C0)[(size_t)row * N + col] = v;
                } else {  // EPI 3
                    if (col < half) {
                        ((unsigned short*)C0)[(size_t)row * half + col] = f2bf(v);
                    } else {
                        float s = v / (1.f + __expf(-v));
                        ((unsigned short*)C1)[(size_t)row * half + col - half] = f2bf(s);
                    }
                }
            }
        }
    }
}

// ---- depthwise conv3 + bias + SiLU: xcpre bf16 -> xcb bf16 ----
__global__ __launch_bounds__(256) void conv_silu_kernel(
    const unsigned short* __restrict__ xcpre, const float* __restrict__ cwf,
    const float* __restrict__ cbf, unsigned short* __restrict__ xcb)
{
    int idx = blockIdx.x * 256 + threadIdx.x;      // over [4096][1536]
    int d   = idx % DINNER;
    int row = idx / DINNER;
    int l   = row % SEQL;
    size_t base = (size_t)row * DINNER + d;
    float acc = cbf[d];
    if (l > 0)        acc += bf2f(xcpre[base - DINNER]) * cwf[d * 3 + 0];
    acc += bf2f(xcpre[base]) * cwf[d * 3 + 1];
    if (l < SEQL - 1) acc += bf2f(xcpre[base + DINNER]) * cwf[d * 3 + 2];
    float s = acc / (1.f + __expf(-acc));
    xcb[base] = f2bf(s);
}

// ---- x_proj: BC[row][32] = xc[row][:] @ xproj_f[1536][32] ----
__global__ __launch_bounds__(128) void xproj_kernel(
    const unsigned short* __restrict__ xcb, const float* __restrict__ wf,
    float* __restrict__ BC)
{
    __shared__ float red[4][32][4];
    const int t = threadIdx.x;
    const int s = t & 31, part = t >> 5;
    const int row0 = blockIdx.x * 4;
    float acc[4] = {0.f, 0.f, 0.f, 0.f};
    for (int k = part * 384; k < (part + 1) * 384; ++k) {
        float wv = wf[k * 32 + s];
        #pragma unroll
        for (int r = 0; r < 4; ++r)
            acc[r] += bf2f(xcb[(size_t)(row0 + r) * DINNER + k]) * wv;
    }
    #pragma unroll
    for (int r = 0; r < 4; ++r) red[part][s][r] = acc[r];
    __syncthreads();
    if (t < 32) {
        #pragma unroll
        for (int r = 0; r < 4; ++r)
            BC[(size_t)(row0 + r) * 32 + t] =
                red[0][t][r] + red[1][t][r] + red[2][t][r] + red[3][t][r];
    }
}

// ---- selective scan + D-skip + silu(z) gating -> yg bf16 ----
__global__ __launch_bounds__(256) void scan_kernel(
    const unsigned short* __restrict__ dlt, const unsigned short* __restrict__ xcb,
    const float* __restrict__ BC, const unsigned short* __restrict__ zg,
    const float* __restrict__ A_log_f, const float* __restrict__ D_f,
    unsigned short* __restrict__ yg)
{
    __shared__ float s_delta[64][16];
    __shared__ float s_xc[64][16];
    __shared__ float s_zg[64][16];
    __shared__ float s_bc[64][32];
    const int t  = threadIdx.x;
    const int n  = t & 15;
    const int dl = t >> 4;
    const int d  = blockIdx.x * 16 + dl;
    const int b  = blockIdx.y;
    const float A_dn = -__expf(A_log_f[d * NSTATE + n]);
    const float Dd   = D_f[d];
    float h = 0.f;

    for (int l0 = 0; l0 < SEQL; l0 += 64) {
        #pragma unroll
        for (int i = 0; i < 4; ++i) {
            int idx = i * 256 + t;
            int li = idx >> 4, dd = idx & 15;
            size_t row = (size_t)(b * SEQL + l0 + li);
            int col = blockIdx.x * 16 + dd;
            s_delta[li][dd] = bf2f(dlt[row * DINNER + col]);
            s_xc[li][dd]    = bf2f(xcb[row * DINNER + col]);
            s_zg[li][dd]    = bf2f(zg[row * DINNER + col]);
        }
        #pragma unroll
        for (int i = 0; i < 8; ++i) {
            int idx = i * 256 + t;
            int li = idx >> 5, ss = idx & 31;
            s_bc[li][ss] = BC[(size_t)(b * SEQL + l0 + li) * 32 + ss];
        }
        __syncthreads();
        for (int li = 0; li < 64; ++li) {
            float dv = s_delta[li][dl];
            float xv = s_xc[li][dl];
            float Bn = s_bc[li][n];
            float Cn = s_bc[li][16 + n];
            float da = __expf(dv * A_dn);
            h = da * h + dv * xv * Bn;
            float y = h * Cn;
            y += __shfl_xor(y, 1);
            y += __shfl_xor(y, 2);
            y += __shfl_xor(y, 4);
            y += __shfl_xor(y, 8);
            if (n == 0) {
                float ygv = (y + Dd * xv) * s_zg[li][dl];
                yg[(size_t)(b * SEQL + l0 + li) * DINNER + d] = f2bf(ygv);
            }
        }
        __syncthreads();
    }
}

__global__ void guard_kernel(float* out, int code)
{
    if (threadIdx.x == 0 && blockIdx.x == 0 && code) out[0] = (float)code;
}

extern "C" void kernel_launch(void* const* d_in, const int* in_sizes, int n_in,
                              void* d_out, int out_size, void* d_ws, size_t ws_size,
                              hipStream_t stream) {
    static const int EXPECTED[10] = {3145728, 2359296, 4608, 1536, 49152,
                                     2359296, 1536, 24576, 1536, 1179648};
    bool ok = (n_in == 10);
    if (ok) for (int i = 0; i < 10; ++i) ok = ok && (in_sizes[i] == EXPECTED[i]);
    int code = 0;
    if (!ok) code = 2000;
    else if (ws_size < 58458112ULL) code = 3000;
    if (code) { guard_kernel<<<1, 64, 0, stream>>>((float*)d_out, code); return; }

    const void* x       = d_in[0];
    const void* in_w    = d_in[1];
    const void* conv_w  = d_in[2];
    const void* conv_b  = d_in[3];
    const void* xproj_w = d_in[4];
    const void* dt_w    = d_in[5];
    const void* dt_b    = d_in[6];
    const void* A_log   = d_in[7];
    const void* Dvec    = d_in[8];
    const void* out_w   = d_in[9];

    char* ws = (char*)d_ws;
    // f32 param block [0, 331776)
    float* conv_w_f = (float*)(ws + 0);        // 4608
    float* conv_b_f = (float*)(ws + 18432);    // 1536
    float* dt_b_f   = (float*)(ws + 24576);    // 1536
    float* A_log_f  = (float*)(ws + 30720);    // 24576
    float* D_f      = (float*)(ws + 129024);   // 1536
    float* xproj_f  = (float*)(ws + 135168);   // 49152
    // total footprint 58458112 B (~56 MB)
    unsigned short* xb    = (unsigned short*)(ws + 524288);    // [4096][768]  (dead after gemm1)
    unsigned short* inT   = (unsigned short*)(ws + 6815744);   // [3072][768]  (dead after gemm1)
    unsigned short* yg    = (unsigned short*)(ws + 524288);    // [4096][1536] alias xb+inT
    unsigned short* dtT   = (unsigned short*)(ws + 13107200);  // [1536][1536]
    unsigned short* outT  = (unsigned short*)(ws + 17825792);  // [768][1536]
    unsigned short* xcpre = (unsigned short*)(ws + 20185088);  // [4096][1536] (dead after conv)
    unsigned short* dlt   = xcpre;                             // alias (gemm2 out)
    float*          BC    = (float*)(ws + 32768000);           // [4096][32]
    unsigned short* zg    = (unsigned short*)(ws + 33292288);  // [4096][1536] silu(z)
    unsigned short* xcb   = (unsigned short*)(ws + 45875200);  // [4096][1536]

    cvt_params_kernel<<<324, 256, 0, stream>>>(conv_w, conv_b, dt_b, A_log, Dvec, xproj_w,
                                               (float*)ws);
    cvt_x_kernel<<<3072, 256, 0, stream>>>(x, xb);
    transpose_any<<<dim3(3072 / 32, 768 / 32), 256, 0, stream>>>(in_w, inT, 768, 3072);
    transpose_any<<<dim3(1536 / 32, 1536 / 32), 256, 0, stream>>>(dt_w, dtT, 1536, 1536);
    transpose_any<<<dim3(768 / 32, 1536 / 32), 256, 0, stream>>>(out_w, outT, 1536, 768);

    // xz = x @ in_w: cols<1536 -> xcpre bf16, cols>=1536 -> silu -> zg bf16
    gemm_kernel<3><<<dim3(32, 24), 256, 0, stream>>>(xb, inT, (void*)xcpre, (void*)zg,
                                                     nullptr, 4096, 3072, 768);
    conv_silu_kernel<<<(4096 * DINNER) / 256, 256, 0, stream>>>(xcpre, conv_w_f, conv_b_f, xcb);
    xproj_kernel<<<1024, 128, 0, stream>>>(xcb, xproj_f, BC);
    // delta = softplus(xc @ dt_w + dt_b) -> bf16 (overwrites xcpre)
    gemm_kernel<1><<<dim3(32, 12), 256, 0, stream>>>(xcb, dtT, (void*)dlt, nullptr,
                                                     dt_b_f, 4096, 1536, 1536);
    scan_kernel<<<dim3(96, 2), 256, 0, stream>>>(dlt, xcb, BC, zg, A_log_f, D_f, yg);
    // out = yg @ out_w -> FP32 d_out
    gemm_kernel<2><<<dim3(32, 6), 256, 0, stream>>>(yg, outT, d_out, nullptr,
                                                    nullptr, 4096, 768, 1536);
}

// Round 8
// 488.277 us; speedup vs baseline: 1.9417x; 1.9417x over previous
//
#include <hip/hip_runtime.h>
#include <cmath>

// SimplifiedSSM: B=2, L=2048, d_model=768, d_state=16, d_inner=1536
// ROUND 8: chunked-parallel scan (R7's scan was 614us at 9% occupancy).
#define DMODEL 768
#define DINNER 1536
#define NSTATE 16
#define SEQL   2048
#define LDSS   56      // LDS row stride in shorts: 112B -> every row 16B-aligned
#define NCHUNK 8
#define CHLEN  256     // SEQL / NCHUNK

#define DT_F32  0
#define DT_BF16 1
#define DT_ZERO 2

typedef __bf16 bf16x8 __attribute__((ext_vector_type(8)));
typedef float  f32x4  __attribute__((ext_vector_type(4)));

__device__ __forceinline__ float bf2f(unsigned short h) {
    union { unsigned u; float f; } v; v.u = ((unsigned)h) << 16; return v.f;
}
__device__ __forceinline__ unsigned short f2bf(float f) {
    union { float f; unsigned u; } v; v.f = f;
    unsigned r = (v.u + 0x7FFFu + ((v.u >> 16) & 1u)) >> 16;
    return (unsigned short)r;
}
__device__ int detect_dtype(const void* p) {
    const unsigned* u = (const unsigned*)p;
    int nzlo = 0, band = 0, anynz = 0;
    for (int i = 0; i < 64; ++i) {
        unsigned w = u[i];
        anynz |= (w != 0);
        unsigned lo = w & 0xFFFFu;
        if (lo) {
            ++nzlo;
            unsigned e8 = (lo >> 7) & 0xFF;
            if (e8 >= 0x60 && e8 <= 0x8E) ++band;
        }
    }
    if (nzlo >= 8) return (band * 2 > nzlo) ? DT_BF16 : DT_F32;
    return anynz ? DT_F32 : DT_ZERO;
}
__device__ __forceinline__ float LD(const void* p, size_t i, int dt) {
    if (dt == DT_BF16) return bf2f(((const unsigned short*)p)[i]);
    if (dt == DT_F32)  return ((const float*)p)[i];
    return 0.f;
}

// ---- x -> bf16 ----
__global__ __launch_bounds__(256) void cvt_x_kernel(
    const void* __restrict__ x, unsigned short* __restrict__ xb)
{
    __shared__ int s_dt;
    if (threadIdx.x == 0) s_dt = detect_dtype(x);
    __syncthreads();
    const int dt = s_dt;
    size_t i = ((size_t)blockIdx.x * 256 + threadIdx.x) * 4;
    ushort4 o;
    o.x = f2bf(LD(x, i + 0, dt)); o.y = f2bf(LD(x, i + 1, dt));
    o.z = f2bf(LD(x, i + 2, dt)); o.w = f2bf(LD(x, i + 3, dt));
    *(ushort4*)&xb[i] = o;
}

// ---- small params -> f32 ----
__global__ __launch_bounds__(256) void cvt_params_kernel(
    const void* cw, const void* cb, const void* db, const void* Al,
    const void* Dv, const void* xp, float* __restrict__ out)
{
    __shared__ int dts[6];
    if (threadIdx.x == 0) {
        dts[0] = detect_dtype(cw); dts[1] = detect_dtype(cb);
        dts[2] = detect_dtype(db); dts[3] = detect_dtype(Al);
        dts[4] = detect_dtype(Dv); dts[5] = detect_dtype(xp);
    }
    __syncthreads();
    int g = blockIdx.x * 256 + threadIdx.x;
    if (g >= 82944) return;
    const void* src; int local; int which;
    if      (g <  4608) { src = cw; local = g;         which = 0; }
    else if (g <  6144) { src = cb; local = g - 4608;  which = 1; }
    else if (g <  7680) { src = db; local = g - 6144;  which = 2; }
    else if (g < 32256) { src = Al; local = g - 7680;  which = 3; }
    else if (g < 33792) { src = Dv; local = g - 32256; which = 4; }
    else                { src = xp; local = g - 33792; which = 5; }
    out[g] = LD(src, local, dts[which]);
}

// ---- transpose: in[R][C] -> out[C][R] bf16 ----
__global__ __launch_bounds__(256) void transpose_any(
    const void* __restrict__ in, unsigned short* __restrict__ out, int R, int C)
{
    __shared__ unsigned short tile[32][33];
    __shared__ int s_dt;
    if (threadIdx.x == 0) s_dt = detect_dtype(in);
    __syncthreads();
    const int dt = s_dt;
    const int t = threadIdx.x;
    const int tx = t & 31, ty = t >> 5;
    const int bx = blockIdx.x * 32, by = blockIdx.y * 32;
    #pragma unroll
    for (int i = 0; i < 4; ++i) {
        int r = by + ty + i * 8;
        tile[ty + i * 8][tx] = f2bf(LD(in, (size_t)r * C + bx + tx, dt));
    }
    __syncthreads();
    #pragma unroll
    for (int i = 0; i < 4; ++i) {
        int c = bx + ty + i * 8;
        out[(size_t)c * R + by + tx] = tile[tx][ty + i * 8];
    }
}

// ---- MFMA GEMM: C = A[M][K] @ Bt[N][K]^T ----
// EPI 1: bf16 C0 = softplus(v + biasf[col])
// EPI 2: f32  C0 = v (final output)
// EPI 3: col < N/2 -> bf16 C0 = v ; else bf16 C1 = silu(v)
template<int EPI>
__global__ __launch_bounds__(256) void gemm_kernel(
    const unsigned short* __restrict__ A, const unsigned short* __restrict__ Bt,
    void* __restrict__ C0, void* __restrict__ C1, const float* __restrict__ biasf,
    int M, int N, int K)
{
    __shared__ __align__(16) unsigned short As[128 * LDSS];
    __shared__ __align__(16) unsigned short Bs[128 * LDSS];
    const int t    = threadIdx.x;
    const int m0   = blockIdx.x * 128;
    const int n0   = blockIdx.y * 128;
    const int w    = t >> 6;
    const int lane = t & 63;
    const int wm   = (w >> 1) * 64, wn = (w & 1) * 64;
    const int lm   = lane & 15, quad = lane >> 4;

    f32x4 acc[4][4] = {};

    for (int k0 = 0; k0 < K; k0 += 32) {
        #pragma unroll
        for (int i = 0; i < 2; ++i) {
            int id = t + i * 256;
            int r = id >> 2, c = (id & 3) * 8;
            *(uint4*)&As[r * LDSS + c] = *(const uint4*)&A[(size_t)(m0 + r) * K + k0 + c];
            *(uint4*)&Bs[r * LDSS + c] = *(const uint4*)&Bt[(size_t)(n0 + r) * K + k0 + c];
        }
        __syncthreads();
        bf16x8 af[4], bfr[4];
        #pragma unroll
        for (int i = 0; i < 4; ++i)
            af[i] = *(const bf16x8*)&As[(wm + i * 16 + lm) * LDSS + quad * 8];
        #pragma unroll
        for (int j = 0; j < 4; ++j)
            bfr[j] = *(const bf16x8*)&Bs[(wn + j * 16 + lm) * LDSS + quad * 8];
        #pragma unroll
        for (int i = 0; i < 4; ++i)
            #pragma unroll
            for (int j = 0; j < 4; ++j)
                acc[i][j] = __builtin_amdgcn_mfma_f32_16x16x32_bf16(af[i], bfr[j], acc[i][j], 0, 0, 0);
        __syncthreads();
    }

    const int half = N >> 1;
    #pragma unroll
    for (int i = 0; i < 4; ++i) {
        #pragma unroll
        for (int j = 0; j < 4; ++j) {
            int col = n0 + wn + j * 16 + lm;
            #pragma unroll
            for (int r = 0; r < 4; ++r) {
                int row = m0 + wm + i * 16 + quad * 4 + r;
                float v = acc[i][j][r];
                if (EPI == 1) {
                    v += biasf[col];
                    float sp = (v > 20.f) ? v : log1pf(__expf(v));
                    ((unsigned short*)C0)[(size_t)row * N + col] = f2bf(sp);
                } else if (EPI == 2) {
                    ((float*)C0)[(size_t)row * N + col] = v;
                } else {
                    if (col < half) {
                        ((unsigned short*)C0)[(size_t)row * half + col] = f2bf(v);
                    } else {
                        float s = v / (1.f + __expf(-v));
                        ((unsigned short*)C1)[(size_t)row * half + col - half] = f2bf(s);
                    }
                }
            }
        }
    }
}

// ---- depthwise conv3 + bias + SiLU ----
__global__ __launch_bounds__(256) void conv_silu_kernel(
    const unsigned short* __restrict__ xcpre, const float* __restrict__ cwf,
    const float* __restrict__ cbf, unsigned short* __restrict__ xcb)
{
    int idx = blockIdx.x * 256 + threadIdx.x;
    int d   = idx % DINNER;
    int row = idx / DINNER;
    int l   = row % SEQL;
    size_t base = (size_t)row * DINNER + d;
    float acc = cbf[d];
    if (l > 0)        acc += bf2f(xcpre[base - DINNER]) * cwf[d * 3 + 0];
    acc += bf2f(xcpre[base]) * cwf[d * 3 + 1];
    if (l < SEQL - 1) acc += bf2f(xcpre[base + DINNER]) * cwf[d * 3 + 2];
    float s = acc / (1.f + __expf(-acc));
    xcb[base] = f2bf(s);
}

// ---- x_proj: BC[row][32] = xc[row][:] @ xproj_f[1536][32] ----
__global__ __launch_bounds__(128) void xproj_kernel(
    const unsigned short* __restrict__ xcb, const float* __restrict__ wf,
    float* __restrict__ BC)
{
    __shared__ float red[4][32][4];
    const int t = threadIdx.x;
    const int s = t & 31, part = t >> 5;
    const int row0 = blockIdx.x * 4;
    float acc[4] = {0.f, 0.f, 0.f, 0.f};
    for (int k = part * 384; k < (part + 1) * 384; ++k) {
        float wv = wf[k * 32 + s];
        #pragma unroll
        for (int r = 0; r < 4; ++r)
            acc[r] += bf2f(xcb[(size_t)(row0 + r) * DINNER + k]) * wv;
    }
    #pragma unroll
    for (int r = 0; r < 4; ++r) red[part][s][r] = acc[r];
    __syncthreads();
    if (t < 32) {
        #pragma unroll
        for (int r = 0; r < 4; ++r)
            BC[(size_t)(row0 + r) * 32 + t] =
                red[0][t][r] + red[1][t][r] + red[2][t][r] + red[3][t][r];
    }
}

// ================= chunked scan =================
// h_t = a_t h_{t-1} + u_t ; a = exp(delta*A), u = delta*xc*B.
// Chunk summary: P = prod a, S = chunk-local final h (h0=0). Layout [b][c][d][n].

// Phase A: per-chunk (P,S). grid (96, 16): y = b*8 + c. thread = (n, dl).
__global__ __launch_bounds__(256) void scan_phase_a(
    const unsigned short* __restrict__ dlt, const unsigned short* __restrict__ xcb,
    const float* __restrict__ BC, const float* __restrict__ A_log_f,
    float* __restrict__ P, float* __restrict__ S)
{
    __shared__ float s_delta[64][16];
    __shared__ float s_xc[64][16];
    __shared__ float s_bc[64][32];
    const int t  = threadIdx.x;
    const int n  = t & 15;
    const int dl = t >> 4;
    const int d  = blockIdx.x * 16 + dl;
    const int b  = blockIdx.y >> 3;
    const int c  = blockIdx.y & 7;
    const float A_dn = -__expf(A_log_f[d * NSTATE + n]);
    float Pv = 1.f, Sv = 0.f;

    for (int l0 = 0; l0 < CHLEN; l0 += 64) {
        #pragma unroll
        for (int i = 0; i < 4; ++i) {
            int idx = i * 256 + t;
            int li = idx >> 4, dd = idx & 15;
            size_t row = (size_t)(b * SEQL + c * CHLEN + l0 + li);
            int col = blockIdx.x * 16 + dd;
            s_delta[li][dd] = bf2f(dlt[row * DINNER + col]);
            s_xc[li][dd]    = bf2f(xcb[row * DINNER + col]);
        }
        #pragma unroll
        for (int i = 0; i < 8; ++i) {
            int idx = i * 256 + t;
            int li = idx >> 5, ss = idx & 31;
            s_bc[li][ss] = BC[(size_t)(b * SEQL + c * CHLEN + l0 + li) * 32 + ss];
        }
        __syncthreads();
        for (int li = 0; li < 64; ++li) {
            float dv = s_delta[li][dl];
            float u  = dv * s_xc[li][dl] * s_bc[li][n];
            float a  = __expf(dv * A_dn);
            Pv *= a;
            Sv = a * Sv + u;
        }
        __syncthreads();
    }
    size_t idx = (((size_t)(b * NCHUNK + c)) * DINNER + d) * NSTATE + n;
    P[idx] = Pv;
    S[idx] = Sv;
}

// Phase B: serial combine over chunks. thread per (b,d,n); 49152 threads.
__global__ __launch_bounds__(256) void scan_combine(
    const float* __restrict__ P, const float* __restrict__ S, float* __restrict__ Hin)
{
    int t = blockIdx.x * 256 + threadIdx.x;            // < 2*1536*16
    int b = t / (DINNER * NSTATE);
    int dn = t % (DINNER * NSTATE);
    float H = 0.f;
    for (int c = 0; c < NCHUNK; ++c) {
        size_t idx = ((size_t)(b * NCHUNK + c)) * (DINNER * NSTATE) + dn;
        Hin[idx] = H;
        H = P[idx] * H + S[idx];
    }
}

// Phase C: replay chunk from Hin; y = sum_n h*C; D-skip + silu(z) gate -> yg bf16.
__global__ __launch_bounds__(256) void scan_phase_c(
    const unsigned short* __restrict__ dlt, const unsigned short* __restrict__ xcb,
    const float* __restrict__ BC, const unsigned short* __restrict__ zg,
    const float* __restrict__ A_log_f, const float* __restrict__ D_f,
    const float* __restrict__ Hin, unsigned short* __restrict__ yg)
{
    __shared__ float s_delta[64][16];
    __shared__ float s_xc[64][16];
    __shared__ float s_zg[64][16];
    __shared__ float s_bc[64][32];
    const int t  = threadIdx.x;
    const int n  = t & 15;
    const int dl = t >> 4;
    const int d  = blockIdx.x * 16 + dl;
    const int b  = blockIdx.y >> 3;
    const int c  = blockIdx.y & 7;
    const float A_dn = -__expf(A_log_f[d * NSTATE + n]);
    const float Dd   = D_f[d];
    float h = Hin[(((size_t)(b * NCHUNK + c)) * DINNER + d) * NSTATE + n];

    for (int l0 = 0; l0 < CHLEN; l0 += 64) {
        #pragma unroll
        for (int i = 0; i < 4; ++i) {
            int idx = i * 256 + t;
            int li = idx >> 4, dd = idx & 15;
            size_t row = (size_t)(b * SEQL + c * CHLEN + l0 + li);
            int col = blockIdx.x * 16 + dd;
            s_delta[li][dd] = bf2f(dlt[row * DINNER + col]);
            s_xc[li][dd]    = bf2f(xcb[row * DINNER + col]);
            s_zg[li][dd]    = bf2f(zg[row * DINNER + col]);
        }
        #pragma unroll
        for (int i = 0; i < 8; ++i) {
            int idx = i * 256 + t;
            int li = idx >> 5, ss = idx & 31;
            s_bc[li][ss] = BC[(size_t)(b * SEQL + c * CHLEN + l0 + li) * 32 + ss];
        }
        __syncthreads();
        for (int li = 0; li < 64; ++li) {
            float dv = s_delta[li][dl];
            float xv = s_xc[li][dl];
            float a  = __expf(dv * A_dn);
            h = a * h + dv * xv * s_bc[li][n];
            float y = h * s_bc[li][16 + n];
            y += __shfl_xor(y, 1);
            y += __shfl_xor(y, 2);
            y += __shfl_xor(y, 4);
            y += __shfl_xor(y, 8);
            if (n == 0) {
                float ygv = (y + Dd * xv) * s_zg[li][dl];
                yg[(size_t)(b * SEQL + c * CHLEN + l0 + li) * DINNER + d] = f2bf(ygv);
            }
        }
        __syncthreads();
    }
}

__global__ void guard_kernel(float* out, int code)
{
    if (threadIdx.x == 0 && blockIdx.x == 0 && code) out[0] = (float)code;
}

extern "C" void kernel_launch(void* const* d_in, const int* in_sizes, int n_in,
                              void* d_out, int out_size, void* d_ws, size_t ws_size,
                              hipStream_t stream) {
    static const int EXPECTED[10] = {3145728, 2359296, 4608, 1536, 49152,
                                     2359296, 1536, 24576, 1536, 1179648};
    bool ok = (n_in == 10);
    if (ok) for (int i = 0; i < 10; ++i) ok = ok && (in_sizes[i] == EXPECTED[i]);
    int code = 0;
    if (!ok) code = 2000;
    else if (ws_size < 58458112ULL) code = 3000;
    if (code) { guard_kernel<<<1, 64, 0, stream>>>((float*)d_out, code); return; }

    const void* x       = d_in[0];
    const void* in_w    = d_in[1];
    const void* conv_w  = d_in[2];
    const void* conv_b  = d_in[3];
    const void* xproj_w = d_in[4];
    const void* dt_w    = d_in[5];
    const void* dt_b    = d_in[6];
    const void* A_log   = d_in[7];
    const void* Dvec    = d_in[8];
    const void* out_w   = d_in[9];

    char* ws = (char*)d_ws;
    float* conv_w_f = (float*)(ws + 0);        // 4608
    float* conv_b_f = (float*)(ws + 18432);    // 1536
    float* dt_b_f   = (float*)(ws + 24576);    // 1536
    float* A_log_f  = (float*)(ws + 30720);    // 24576
    float* D_f      = (float*)(ws + 129024);   // 1536
    float* xproj_f  = (float*)(ws + 135168);   // 49152
    // footprint unchanged vs R7 (58458112 B)
    unsigned short* xb    = (unsigned short*)(ws + 524288);    // [4096][768]  (dead after gemm1)
    unsigned short* inT   = (unsigned short*)(ws + 6815744);   // [3072][768]  (dead after gemm1)
    unsigned short* yg    = (unsigned short*)(ws + 524288);    // [4096][1536] alias xb+inT
    unsigned short* dtT   = (unsigned short*)(ws + 13107200);  // [1536][1536] (dead after gemm2)
    // P/S/Hin: 3 x 1572864 B, exactly overlay the dead dtT region
    float*          scanP = (float*)(ws + 13107200);
    float*          scanS = (float*)(ws + 14680064);
    float*          scanH = (float*)(ws + 16252928);
    unsigned short* outT  = (unsigned short*)(ws + 17825792);  // [768][1536]
    unsigned short* xcpre = (unsigned short*)(ws + 20185088);  // [4096][1536] (dead after conv)
    unsigned short* dlt   = xcpre;                             // alias (gemm2 out)
    float*          BC    = (float*)(ws + 32768000);           // [4096][32]
    unsigned short* zg    = (unsigned short*)(ws + 33292288);  // [4096][1536] silu(z)
    unsigned short* xcb   = (unsigned short*)(ws + 45875200);  // [4096][1536]

    cvt_params_kernel<<<324, 256, 0, stream>>>(conv_w, conv_b, dt_b, A_log, Dvec, xproj_w,
                                               (float*)ws);
    cvt_x_kernel<<<3072, 256, 0, stream>>>(x, xb);
    transpose_any<<<dim3(3072 / 32, 768 / 32), 256, 0, stream>>>(in_w, inT, 768, 3072);
    transpose_any<<<dim3(1536 / 32, 1536 / 32), 256, 0, stream>>>(dt_w, dtT, 1536, 1536);
    transpose_any<<<dim3(768 / 32, 1536 / 32), 256, 0, stream>>>(out_w, outT, 1536, 768);

    gemm_kernel<3><<<dim3(32, 24), 256, 0, stream>>>(xb, inT, (void*)xcpre, (void*)zg,
                                                     nullptr, 4096, 3072, 768);
    conv_silu_kernel<<<(4096 * DINNER) / 256, 256, 0, stream>>>(xcpre, conv_w_f, conv_b_f, xcb);
    xproj_kernel<<<1024, 128, 0, stream>>>(xcb, xproj_f, BC);
    gemm_kernel<1><<<dim3(32, 12), 256, 0, stream>>>(xcb, dtT, (void*)dlt, nullptr,
                                                     dt_b_f, 4096, 1536, 1536);
    // chunked scan (dtT dead from here; P/S/Hin overlay it)
    scan_phase_a<<<dim3(96, 16), 256, 0, stream>>>(dlt, xcb, BC, A_log_f, scanP, scanS);
    scan_combine<<<192, 256, 0, stream>>>(scanP, scanS, scanH);
    scan_phase_c<<<dim3(96, 16), 256, 0, stream>>>(dlt, xcb, BC, zg, A_log_f, D_f, scanH, yg);
    gemm_kernel<2><<<dim3(32, 6), 256, 0, stream>>>(yg, outT, d_out, nullptr,
                                                    nullptr, 4096, 768, 1536);
}

// Round 9
// 484.376 us; speedup vs baseline: 1.9574x; 1.0081x over previous
//
#include <hip/hip_runtime.h>
#include <cmath>

// SimplifiedSSM: B=2, L=2048, d_model=768, d_state=16, d_inner=1536
// ROUND 9: NCHUNK 8->16 (full 32-wave/CU occupancy on scan phases A/C).
#define DMODEL 768
#define DINNER 1536
#define NSTATE 16
#define SEQL   2048
#define LDSS   56      // LDS row stride in shorts: 112B -> every row 16B-aligned
#define NCHUNK 16
#define CHLEN  128     // SEQL / NCHUNK

#define DT_F32  0
#define DT_BF16 1
#define DT_ZERO 2

typedef __bf16 bf16x8 __attribute__((ext_vector_type(8)));
typedef float  f32x4  __attribute__((ext_vector_type(4)));

__device__ __forceinline__ float bf2f(unsigned short h) {
    union { unsigned u; float f; } v; v.u = ((unsigned)h) << 16; return v.f;
}
__device__ __forceinline__ unsigned short f2bf(float f) {
    union { float f; unsigned u; } v; v.f = f;
    unsigned r = (v.u + 0x7FFFu + ((v.u >> 16) & 1u)) >> 16;
    return (unsigned short)r;
}
__device__ int detect_dtype(const void* p) {
    const unsigned* u = (const unsigned*)p;
    int nzlo = 0, band = 0, anynz = 0;
    for (int i = 0; i < 64; ++i) {
        unsigned w = u[i];
        anynz |= (w != 0);
        unsigned lo = w & 0xFFFFu;
        if (lo) {
            ++nzlo;
            unsigned e8 = (lo >> 7) & 0xFF;
            if (e8 >= 0x60 && e8 <= 0x8E) ++band;
        }
    }
    if (nzlo >= 8) return (band * 2 > nzlo) ? DT_BF16 : DT_F32;
    return anynz ? DT_F32 : DT_ZERO;
}
__device__ __forceinline__ float LD(const void* p, size_t i, int dt) {
    if (dt == DT_BF16) return bf2f(((const unsigned short*)p)[i]);
    if (dt == DT_F32)  return ((const float*)p)[i];
    return 0.f;
}

// ---- x -> bf16 ----
__global__ __launch_bounds__(256) void cvt_x_kernel(
    const void* __restrict__ x, unsigned short* __restrict__ xb)
{
    __shared__ int s_dt;
    if (threadIdx.x == 0) s_dt = detect_dtype(x);
    __syncthreads();
    const int dt = s_dt;
    size_t i = ((size_t)blockIdx.x * 256 + threadIdx.x) * 4;
    ushort4 o;
    o.x = f2bf(LD(x, i + 0, dt)); o.y = f2bf(LD(x, i + 1, dt));
    o.z = f2bf(LD(x, i + 2, dt)); o.w = f2bf(LD(x, i + 3, dt));
    *(ushort4*)&xb[i] = o;
}

// ---- small params -> f32 ----
__global__ __launch_bounds__(256) void cvt_params_kernel(
    const void* cw, const void* cb, const void* db, const void* Al,
    const void* Dv, const void* xp, float* __restrict__ out)
{
    __shared__ int dts[6];
    if (threadIdx.x == 0) {
        dts[0] = detect_dtype(cw); dts[1] = detect_dtype(cb);
        dts[2] = detect_dtype(db); dts[3] = detect_dtype(Al);
        dts[4] = detect_dtype(Dv); dts[5] = detect_dtype(xp);
    }
    __syncthreads();
    int g = blockIdx.x * 256 + threadIdx.x;
    if (g >= 82944) return;
    const void* src; int local; int which;
    if      (g <  4608) { src = cw; local = g;         which = 0; }
    else if (g <  6144) { src = cb; local = g - 4608;  which = 1; }
    else if (g <  7680) { src = db; local = g - 6144;  which = 2; }
    else if (g < 32256) { src = Al; local = g - 7680;  which = 3; }
    else if (g < 33792) { src = Dv; local = g - 32256; which = 4; }
    else                { src = xp; local = g - 33792; which = 5; }
    out[g] = LD(src, local, dts[which]);
}

// ---- transpose: in[R][C] -> out[C][R] bf16 ----
__global__ __launch_bounds__(256) void transpose_any(
    const void* __restrict__ in, unsigned short* __restrict__ out, int R, int C)
{
    __shared__ unsigned short tile[32][33];
    __shared__ int s_dt;
    if (threadIdx.x == 0) s_dt = detect_dtype(in);
    __syncthreads();
    const int dt = s_dt;
    const int t = threadIdx.x;
    const int tx = t & 31, ty = t >> 5;
    const int bx = blockIdx.x * 32, by = blockIdx.y * 32;
    #pragma unroll
    for (int i = 0; i < 4; ++i) {
        int r = by + ty + i * 8;
        tile[ty + i * 8][tx] = f2bf(LD(in, (size_t)r * C + bx + tx, dt));
    }
    __syncthreads();
    #pragma unroll
    for (int i = 0; i < 4; ++i) {
        int c = bx + ty + i * 8;
        out[(size_t)c * R + by + tx] = tile[tx][ty + i * 8];
    }
}

// ---- MFMA GEMM: C = A[M][K] @ Bt[N][K]^T ----
// EPI 1: bf16 C0 = softplus(v + biasf[col])
// EPI 2: f32  C0 = v (final output)
// EPI 3: col < N/2 -> bf16 C0 = v ; else bf16 C1 = silu(v)
template<int EPI>
__global__ __launch_bounds__(256) void gemm_kernel(
    const unsigned short* __restrict__ A, const unsigned short* __restrict__ Bt,
    void* __restrict__ C0, void* __restrict__ C1, const float* __restrict__ biasf,
    int M, int N, int K)
{
    __shared__ __align__(16) unsigned short As[128 * LDSS];
    __shared__ __align__(16) unsigned short Bs[128 * LDSS];
    const int t    = threadIdx.x;
    const int m0   = blockIdx.x * 128;
    const int n0   = blockIdx.y * 128;
    const int w    = t >> 6;
    const int lane = t & 63;
    const int wm   = (w >> 1) * 64, wn = (w & 1) * 64;
    const int lm   = lane & 15, quad = lane >> 4;

    f32x4 acc[4][4] = {};

    for (int k0 = 0; k0 < K; k0 += 32) {
        #pragma unroll
        for (int i = 0; i < 2; ++i) {
            int id = t + i * 256;
            int r = id >> 2, c = (id & 3) * 8;
            *(uint4*)&As[r * LDSS + c] = *(const uint4*)&A[(size_t)(m0 + r) * K + k0 + c];
            *(uint4*)&Bs[r * LDSS + c] = *(const uint4*)&Bt[(size_t)(n0 + r) * K + k0 + c];
        }
        __syncthreads();
        bf16x8 af[4], bfr[4];
        #pragma unroll
        for (int i = 0; i < 4; ++i)
            af[i] = *(const bf16x8*)&As[(wm + i * 16 + lm) * LDSS + quad * 8];
        #pragma unroll
        for (int j = 0; j < 4; ++j)
            bfr[j] = *(const bf16x8*)&Bs[(wn + j * 16 + lm) * LDSS + quad * 8];
        #pragma unroll
        for (int i = 0; i < 4; ++i)
            #pragma unroll
            for (int j = 0; j < 4; ++j)
                acc[i][j] = __builtin_amdgcn_mfma_f32_16x16x32_bf16(af[i], bfr[j], acc[i][j], 0, 0, 0);
        __syncthreads();
    }

    const int half = N >> 1;
    #pragma unroll
    for (int i = 0; i < 4; ++i) {
        #pragma unroll
        for (int j = 0; j < 4; ++j) {
            int col = n0 + wn + j * 16 + lm;
            #pragma unroll
            for (int r = 0; r < 4; ++r) {
                int row = m0 + wm + i * 16 + quad * 4 + r;
                float v = acc[i][j][r];
                if (EPI == 1) {
                    v += biasf[col];
                    float sp = (v > 20.f) ? v : log1pf(__expf(v));
                    ((unsigned short*)C0)[(size_t)row * N + col] = f2bf(sp);
                } else if (EPI == 2) {
                    ((float*)C0)[(size_t)row * N + col] = v;
                } else {
                    if (col < half) {
                        ((unsigned short*)C0)[(size_t)row * half + col] = f2bf(v);
                    } else {
                        float s = v / (1.f + __expf(-v));
                        ((unsigned short*)C1)[(size_t)row * half + col - half] = f2bf(s);
                    }
                }
            }
        }
    }
}

// ---- depthwise conv3 + bias + SiLU ----
__global__ __launch_bounds__(256) void conv_silu_kernel(
    const unsigned short* __restrict__ xcpre, const float* __restrict__ cwf,
    const float* __restrict__ cbf, unsigned short* __restrict__ xcb)
{
    int idx = blockIdx.x * 256 + threadIdx.x;
    int d   = idx % DINNER;
    int row = idx / DINNER;
    int l   = row % SEQL;
    size_t base = (size_t)row * DINNER + d;
    float acc = cbf[d];
    if (l > 0)        acc += bf2f(xcpre[base - DINNER]) * cwf[d * 3 + 0];
    acc += bf2f(xcpre[base]) * cwf[d * 3 + 1];
    if (l < SEQL - 1) acc += bf2f(xcpre[base + DINNER]) * cwf[d * 3 + 2];
    float s = acc / (1.f + __expf(-acc));
    xcb[base] = f2bf(s);
}

// ---- x_proj: BC[row][32] = xc[row][:] @ xproj_f[1536][32] ----
__global__ __launch_bounds__(128) void xproj_kernel(
    const unsigned short* __restrict__ xcb, const float* __restrict__ wf,
    float* __restrict__ BC)
{
    __shared__ float red[4][32][4];
    const int t = threadIdx.x;
    const int s = t & 31, part = t >> 5;
    const int row0 = blockIdx.x * 4;
    float acc[4] = {0.f, 0.f, 0.f, 0.f};
    for (int k = part * 384; k < (part + 1) * 384; ++k) {
        float wv = wf[k * 32 + s];
        #pragma unroll
        for (int r = 0; r < 4; ++r)
            acc[r] += bf2f(xcb[(size_t)(row0 + r) * DINNER + k]) * wv;
    }
    #pragma unroll
    for (int r = 0; r < 4; ++r) red[part][s][r] = acc[r];
    __syncthreads();
    if (t < 32) {
        #pragma unroll
        for (int r = 0; r < 4; ++r)
            BC[(size_t)(row0 + r) * 32 + t] =
                red[0][t][r] + red[1][t][r] + red[2][t][r] + red[3][t][r];
    }
}

// ================= chunked scan =================
// h_t = a_t h_{t-1} + u_t ; a = exp(delta*A), u = delta*xc*B.
// P = prod a (bf16), S = chunk-local final h (f32). Layout [b][c][d][n].
// Phase B overwrites S with Hin (carried-in state) in place.

// Phase A: per-chunk (P,S). grid (96, 32): y = b*16 + c. thread = (n, dl).
__global__ __launch_bounds__(256) void scan_phase_a(
    const unsigned short* __restrict__ dlt, const unsigned short* __restrict__ xcb,
    const float* __restrict__ BC, const float* __restrict__ A_log_f,
    unsigned short* __restrict__ P, float* __restrict__ S)
{
    __shared__ float s_delta[64][16];
    __shared__ float s_xc[64][16];
    __shared__ float s_bc[64][32];
    const int t  = threadIdx.x;
    const int n  = t & 15;
    const int dl = t >> 4;
    const int d  = blockIdx.x * 16 + dl;
    const int b  = blockIdx.y >> 4;
    const int c  = blockIdx.y & 15;
    const float A_dn = -__expf(A_log_f[d * NSTATE + n]);
    float Pv = 1.f, Sv = 0.f;

    for (int l0 = 0; l0 < CHLEN; l0 += 64) {
        #pragma unroll
        for (int i = 0; i < 4; ++i) {
            int idx = i * 256 + t;
            int li = idx >> 4, dd = idx & 15;
            size_t row = (size_t)(b * SEQL + c * CHLEN + l0 + li);
            int col = blockIdx.x * 16 + dd;
            s_delta[li][dd] = bf2f(dlt[row * DINNER + col]);
            s_xc[li][dd]    = bf2f(xcb[row * DINNER + col]);
        }
        #pragma unroll
        for (int i = 0; i < 8; ++i) {
            int idx = i * 256 + t;
            int li = idx >> 5, ss = idx & 31;
            s_bc[li][ss] = BC[(size_t)(b * SEQL + c * CHLEN + l0 + li) * 32 + ss];
        }
        __syncthreads();
        for (int li = 0; li < 64; ++li) {
            float dv = s_delta[li][dl];
            float u  = dv * s_xc[li][dl] * s_bc[li][n];
            float a  = __expf(dv * A_dn);
            Pv *= a;
            Sv = a * Sv + u;
        }
        __syncthreads();
    }
    size_t idx = (((size_t)(b * NCHUNK + c)) * DINNER + d) * NSTATE + n;
    P[idx] = f2bf(Pv);
    S[idx] = Sv;
}

// Phase B: serial combine over chunks; writes Hin into S in place.
__global__ __launch_bounds__(256) void scan_combine(
    const unsigned short* __restrict__ P, float* __restrict__ S)
{
    int t = blockIdx.x * 256 + threadIdx.x;            // < 2*1536*16
    int b = t / (DINNER * NSTATE);
    int dn = t % (DINNER * NSTATE);
    float H = 0.f;
    for (int c = 0; c < NCHUNK; ++c) {
        size_t idx = ((size_t)(b * NCHUNK + c)) * (DINNER * NSTATE) + dn;
        float Pv = bf2f(P[idx]);
        float Sv = S[idx];
        S[idx] = H;                 // Hin for chunk c
        H = Pv * H + Sv;
    }
}

// Phase C: replay chunk from Hin(=S); y = sum_n h*C; D-skip + silu(z) gate -> yg bf16.
__global__ __launch_bounds__(256) void scan_phase_c(
    const unsigned short* __restrict__ dlt, const unsigned short* __restrict__ xcb,
    const float* __restrict__ BC, const unsigned short* __restrict__ zg,
    const float* __restrict__ A_log_f, const float* __restrict__ D_f,
    const float* __restrict__ Hin, unsigned short* __restrict__ yg)
{
    __shared__ float s_delta[64][16];
    __shared__ float s_xc[64][16];
    __shared__ float s_zg[64][16];
    __shared__ float s_bc[64][32];
    const int t  = threadIdx.x;
    const int n  = t & 15;
    const int dl = t >> 4;
    const int d  = blockIdx.x * 16 + dl;
    const int b  = blockIdx.y >> 4;
    const int c  = blockIdx.y & 15;
    const float A_dn = -__expf(A_log_f[d * NSTATE + n]);
    const float Dd   = D_f[d];
    float h = Hin[(((size_t)(b * NCHUNK + c)) * DINNER + d) * NSTATE + n];

    for (int l0 = 0; l0 < CHLEN; l0 += 64) {
        #pragma unroll
        for (int i = 0; i < 4; ++i) {
            int idx = i * 256 + t;
            int li = idx >> 4, dd = idx & 15;
            size_t row = (size_t)(b * SEQL + c * CHLEN + l0 + li);
            int col = blockIdx.x * 16 + dd;
            s_delta[li][dd] = bf2f(dlt[row * DINNER + col]);
            s_xc[li][dd]    = bf2f(xcb[row * DINNER + col]);
            s_zg[li][dd]    = bf2f(zg[row * DINNER + col]);
        }
        #pragma unroll
        for (int i = 0; i < 8; ++i) {
            int idx = i * 256 + t;
            int li = idx >> 5, ss = idx & 31;
            s_bc[li][ss] = BC[(size_t)(b * SEQL + c * CHLEN + l0 + li) * 32 + ss];
        }
        __syncthreads();
        for (int li = 0; li < 64; ++li) {
            float dv = s_delta[li][dl];
            float xv = s_xc[li][dl];
            float a  = __expf(dv * A_dn);
            h = a * h + dv * xv * s_bc[li][n];
            float y = h * s_bc[li][16 + n];
            y += __shfl_xor(y, 1);
            y += __shfl_xor(y, 2);
            y += __shfl_xor(y, 4);
            y += __shfl_xor(y, 8);
            if (n == 0) {
                float ygv = (y + Dd * xv) * s_zg[li][dl];
                yg[(size_t)(b * SEQL + c * CHLEN + l0 + li) * DINNER + d] = f2bf(ygv);
            }
        }
        __syncthreads();
    }
}

__global__ void guard_kernel(float* out, int code)
{
    if (threadIdx.x == 0 && blockIdx.x == 0 && code) out[0] = (float)code;
}

extern "C" void kernel_launch(void* const* d_in, const int* in_sizes, int n_in,
                              void* d_out, int out_size, void* d_ws, size_t ws_size,
                              hipStream_t stream) {
    static const int EXPECTED[10] = {3145728, 2359296, 4608, 1536, 49152,
                                     2359296, 1536, 24576, 1536, 1179648};
    bool ok = (n_in == 10);
    if (ok) for (int i = 0; i < 10; ++i) ok = ok && (in_sizes[i] == EXPECTED[i]);
    int code = 0;
    if (!ok) code = 2000;
    else if (ws_size < 58458112ULL) code = 3000;
    if (code) { guard_kernel<<<1, 64, 0, stream>>>((float*)d_out, code); return; }

    const void* x       = d_in[0];
    const void* in_w    = d_in[1];
    const void* conv_w  = d_in[2];
    const void* conv_b  = d_in[3];
    const void* xproj_w = d_in[4];
    const void* dt_w    = d_in[5];
    const void* dt_b    = d_in[6];
    const void* A_log   = d_in[7];
    const void* Dvec    = d_in[8];
    const void* out_w   = d_in[9];

    char* ws = (char*)d_ws;
    float* conv_w_f = (float*)(ws + 0);        // 4608
    float* conv_b_f = (float*)(ws + 18432);    // 1536
    float* dt_b_f   = (float*)(ws + 24576);    // 1536
    float* A_log_f  = (float*)(ws + 30720);    // 24576
    float* D_f      = (float*)(ws + 129024);   // 1536
    float* xproj_f  = (float*)(ws + 135168);   // 49152
    // footprint unchanged vs R7/R8 (58458112 B)
    unsigned short* xb    = (unsigned short*)(ws + 524288);    // [4096][768]  (dead after gemm1)
    unsigned short* inT   = (unsigned short*)(ws + 6815744);   // [3072][768]  (dead after gemm1)
    unsigned short* yg    = (unsigned short*)(ws + 524288);    // [4096][1536] alias xb+inT
    unsigned short* dtT   = (unsigned short*)(ws + 13107200);  // [1536][1536] (dead after gemm2)
    // P (bf16, 1572864 B) + S (f32, 3145728 B) exactly overlay dead dtT (4718592 B)
    unsigned short* scanP = (unsigned short*)(ws + 13107200);
    float*          scanS = (float*)(ws + 14680064);
    unsigned short* outT  = (unsigned short*)(ws + 17825792);  // [768][1536]
    unsigned short* xcpre = (unsigned short*)(ws + 20185088);  // [4096][1536] (dead after conv)
    unsigned short* dlt   = xcpre;                             // alias (gemm2 out)
    float*          BC    = (float*)(ws + 32768000);           // [4096][32]
    unsigned short* zg    = (unsigned short*)(ws + 33292288);  // [4096][1536] silu(z)
    unsigned short* xcb   = (unsigned short*)(ws + 45875200);  // [4096][1536]

    cvt_params_kernel<<<324, 256, 0, stream>>>(conv_w, conv_b, dt_b, A_log, Dvec, xproj_w,
                                               (float*)ws);
    cvt_x_kernel<<<3072, 256, 0, stream>>>(x, xb);
    transpose_any<<<dim3(3072 / 32, 768 / 32), 256, 0, stream>>>(in_w, inT, 768, 3072);
    transpose_any<<<dim3(1536 / 32, 1536 / 32), 256, 0, stream>>>(dt_w, dtT, 1536, 1536);
    transpose_any<<<dim3(768 / 32, 1536 / 32), 256, 0, stream>>>(out_w, outT, 1536, 768);

    gemm_kernel<3><<<dim3(32, 24), 256, 0, stream>>>(xb, inT, (void*)xcpre, (void*)zg,
                                                     nullptr, 4096, 3072, 768);
    conv_silu_kernel<<<(4096 * DINNER) / 256, 256, 0, stream>>>(xcpre, conv_w_f, conv_b_f, xcb);
    xproj_kernel<<<1024, 128, 0, stream>>>(xcb, xproj_f, BC);
    gemm_kernel<1><<<dim3(32, 12), 256, 0, stream>>>(xcb, dtT, (void*)dlt, nullptr,
                                                     dt_b_f, 4096, 1536, 1536);
    // chunked scan (dtT dead from here; P/S overlay it; S becomes Hin after combine)
    scan_phase_a<<<dim3(96, 32), 256, 0, stream>>>(dlt, xcb, BC, A_log_f, scanP, scanS);
    scan_combine<<<192, 256, 0, stream>>>(scanP, scanS);
    scan_phase_c<<<dim3(96, 32), 256, 0, stream>>>(dlt, xcb, BC, zg, A_log_f, D_f, scanS, yg);
    gemm_kernel<2><<<dim3(32, 6), 256, 0, stream>>>(yg, outT, d_out, nullptr,
                                                    nullptr, 4096, 768, 1536);
}